// Round 8
// baseline (253.189 us; speedup 1.0000x reference)
//
#include <hip/hip_runtime.h>
#include <hip/hip_bf16.h>

// Problem constants (AttentionConv2d): B=32, CIN=256, H=W=32 -> N=1024,
// DK=DV=128, HEADS=8 -> per-head d=16, OUT=256.
#define BATCH 32
#define CIN   256
#define NPOS  1024
#define DKC   128
#define DVC   128
#define HEADS 8
#define OUTC  256

typedef __bf16 bf16x8 __attribute__((ext_vector_type(8)));
typedef __bf16 bf16x4 __attribute__((ext_vector_type(4)));
typedef float  f32x4  __attribute__((ext_vector_type(4)));
typedef float  f32x16 __attribute__((ext_vector_type(16)));

// q pre-scale: dk^-0.5 * log2(e), so attention can use raw exp2.
#define QSCALE 0.3606737602f

__device__ inline bf16x8 load8(const __bf16* p) {
    return *reinterpret_cast<const bf16x8*>(p);
}
__device__ inline f32x4 fzero4() {
    f32x4 z;
#pragma unroll
    for (int i = 0; i < 4; ++i) z[i] = 0.0f;
    return z;
}
__device__ inline float fexp2(float x) {
#if __has_builtin(__builtin_amdgcn_exp2f)
    return __builtin_amdgcn_exp2f(x);
#else
    return exp2f(x);
#endif
}

// ---------------------------------------------------------------------------
// Kernel D: dtype detector (fp32-as-bf16 halfwords have huge exponents).
// ---------------------------------------------------------------------------
__global__ __launch_bounds__(256) void detect_dtype(const unsigned short* __restrict__ xraw,
                                                    int* __restrict__ flag) {
    __shared__ int s;
    if (threadIdx.x == 0) s = 0;
    __syncthreads();
    int cnt = 0;
#pragma unroll
    for (int j = 0; j < 64; ++j) {
        unsigned short u = xraw[threadIdx.x * 64 + j];
        unsigned int e = (u >> 7) & 0xFF;
        if (e >= 0x92) cnt++;
    }
    if (cnt) atomicAdd(&s, cnt);
    __syncthreads();
    if (threadIdx.x == 0) *flag = (s > 0) ? 1 : 0;
}

// ---------------------------------------------------------------------------
// Kernel C: convert all weight/bias tensors to canonical bf16 in one launch.
// ---------------------------------------------------------------------------
#define CVT_N0 98304   // w_qkv 384*256
#define CVT_N1 (CVT_N0 + 384)
#define CVT_N2 (CVT_N1 + 16384)  // w_attn 128*128
#define CVT_N3 (CVT_N2 + 128)
#define CVT_N4 (CVT_N3 + 32768)  // w_out 128*256
#define CVT_N5 (CVT_N4 + 128)
__global__ __launch_bounds__(256) void convert_all(
    const void* __restrict__ w_qkv, const void* __restrict__ b_qkv,
    const void* __restrict__ w_attn, const void* __restrict__ b_attn,
    const void* __restrict__ w_out, const void* __restrict__ b_out,
    __bf16* __restrict__ w_qkvc, __bf16* __restrict__ b_qkvc,
    __bf16* __restrict__ w_attnc, __bf16* __restrict__ b_attnc,
    __bf16* __restrict__ w_outc, __bf16* __restrict__ b_outc,
    const int* __restrict__ flag) {
    int i = blockIdx.x * 256 + threadIdx.x;
    const void* src; __bf16* dst; int off;
    if      (i < CVT_N0) { src = w_qkv;  dst = w_qkvc;  off = 0; }
    else if (i < CVT_N1) { src = b_qkv;  dst = b_qkvc;  off = CVT_N0; }
    else if (i < CVT_N2) { src = w_attn; dst = w_attnc; off = CVT_N1; }
    else if (i < CVT_N3) { src = b_attn; dst = b_attnc; off = CVT_N2; }
    else if (i < CVT_N4) { src = w_out;  dst = w_outc;  off = CVT_N3; }
    else if (i < CVT_N5) { src = b_out;  dst = b_outc;  off = CVT_N4; }
    else return;
    int j = i - off;
    if (*flag) dst[j] = (__bf16)((const float*)src)[j];
    else       dst[j] = ((const __bf16*)src)[j];
}

// ---------------------------------------------------------------------------
// Kernel 0: transpose+convert x [B][C][N] -> xT(bf16) [B][N][C].
// Two-phase LDS transpose, conflict-free (68 pad), vector loads/stores.
// grid (N/64=16, C/64=4, B=32) = 2048 blocks, block 256.
// ---------------------------------------------------------------------------
__global__ __launch_bounds__(256) void transpose_x(const void* __restrict__ xv,
                                                   __bf16* __restrict__ xT,
                                                   const int* __restrict__ flag) {
    __shared__ __bf16 tile[64][68];
    bool isf32 = (*flag != 0);
    int b  = blockIdx.z;
    int n0 = blockIdx.x * 64;
    int c0 = blockIdx.y * 64;
    int t  = threadIdx.x;

    int nl = (t & 15) * 4;
    int cl = t >> 4;
#pragma unroll
    for (int i = 0; i < 4; ++i) {
        int c = cl + i * 16;
        size_t base = ((size_t)b * CIN + c0 + c) * NPOS + n0 + nl;
        if (isf32) {
            float4 v = *reinterpret_cast<const float4*>((const float*)xv + base);
            tile[c][nl + 0] = (__bf16)v.x;
            tile[c][nl + 1] = (__bf16)v.y;
            tile[c][nl + 2] = (__bf16)v.z;
            tile[c][nl + 3] = (__bf16)v.w;
        } else {
            bf16x4 v = *reinterpret_cast<const bf16x4*>((const __bf16*)xv + base);
#pragma unroll
            for (int j = 0; j < 4; ++j) tile[c][nl + j] = v[j];
        }
    }
    __syncthreads();
    int cl2 = (t & 15) * 4;
    int nl2 = t >> 4;
#pragma unroll
    for (int i = 0; i < 4; ++i) {
        int n = nl2 + i * 16;
        bf16x4 v;
#pragma unroll
        for (int j = 0; j < 4; ++j) v[j] = tile[cl2 + j][n];
        *reinterpret_cast<bf16x4*>(
            xT + ((size_t)b * NPOS + n0 + n) * CIN + c0 + cl2) = v;
    }
}

// ---------------------------------------------------------------------------
// Kernel 1: fused QKV + parallel-conv GEMM reading xT (no LDS, all frag
// loads 16B coalesced from global; weights L2-resident across batches).
// rows 0..383 = w_qkv (q/k/v), 384..511 = w_out -> d_out channels 0..127.
// grid (N/64=16, 8, B=32) = 4096 blocks (16 blocks/CU oversub), block 256.
// ---------------------------------------------------------------------------
__global__ __launch_bounds__(256) void qkv_conv_gemm(
    const __bf16* __restrict__ xT,     // [B][N][C]
    const __bf16* __restrict__ w_qkv,  // [384][256]
    const __bf16* __restrict__ b_qkv,  // [384]
    const __bf16* __restrict__ w_out,  // [128][256]
    const __bf16* __restrict__ b_out,  // [128]
    __bf16* __restrict__ q_ws,         // [B*H][N][16]
    __bf16* __restrict__ k_ws,         // [B*H][N][16]
    __bf16* __restrict__ v_ws,         // [B*H][16][N]
    void* __restrict__ out,            // [B][256][N], dtype per flag
    const int* __restrict__ flag)
{
    bool isf32 = (*flag != 0);
    int b    = blockIdx.z;
    int mt   = blockIdx.y;
    int nt   = blockIdx.x;
    int wave = threadIdx.x >> 6;
    int lane = threadIdx.x & 63;
    int quad = lane >> 4, colid = lane & 15;

    int row0 = mt * 64 + wave * 16;
    int n0   = nt * 64;

    int arow = row0 + colid;
    const __bf16* wrow =
        (arow < 384) ? (w_qkv + (size_t)arow * CIN) : (w_out + (size_t)(arow - 384) * CIN);
    const __bf16* xb = xT + ((size_t)b * NPOS + n0) * CIN;

    f32x4 acc[4];
#pragma unroll
    for (int st = 0; st < 4; ++st) acc[st] = fzero4();

#pragma unroll
    for (int k0 = 0; k0 < CIN; k0 += 32) {
        bf16x8 a = load8(wrow + k0 + quad * 8);
#pragma unroll
        for (int st = 0; st < 4; ++st) {
            bf16x8 bb = load8(xb + (size_t)(st * 16 + colid) * CIN + k0 + quad * 8);
            acc[st] = __builtin_amdgcn_mfma_f32_16x16x32_bf16(a, bb, acc[st], 0, 0, 0);
        }
    }

#pragma unroll
    for (int r = 0; r < 4; ++r) {
        int o = row0 + quad * 4 + r;
        float bias = (o < 384) ? (float)b_qkv[o] : (float)b_out[o - 384];
#pragma unroll
        for (int st = 0; st < 4; ++st) {
            int n = n0 + st * 16 + colid;
            float v = acc[st][r] + bias;
            if (o < DKC) {  // q, pre-scaled by dk^-0.5 * log2(e) for exp2 softmax
                int h = o >> 4, d = o & 15;
                q_ws[(((size_t)b * HEADS + h) * NPOS + n) * 16 + d] = (__bf16)(v * QSCALE);
            } else if (o < 2 * DKC) {  // k
                int oo = o - DKC;
                k_ws[(((size_t)b * HEADS + (oo >> 4)) * NPOS + n) * 16 + (oo & 15)] = (__bf16)v;
            } else if (o < 384) {  // v -> [bh][d][n]
                int oo = o - 2 * DKC;
                v_ws[(((size_t)b * HEADS + (oo >> 4)) * 16 + (oo & 15)) * NPOS + n] = (__bf16)v;
            } else {  // conv branch -> output channels 0..127
                size_t oi = ((size_t)b * OUTC + (o - 384)) * NPOS + n;
                if (isf32) ((float*)out)[oi] = v;
                else       ((__bf16*)out)[oi] = (__bf16)v;
            }
        }
    }
}

// ---------------------------------------------------------------------------
// Kernel 2: attention on NATIVE MFMA shapes (unchanged from round 7).
// grid (N/128=8, B*H=256), block 256 (4 independent waves).
// ---------------------------------------------------------------------------
#define PSTR 80  // bytes per query row in the P strip (16B-aligned, odd*16)
__global__ __launch_bounds__(256) void attention_kernel(
    const __bf16* __restrict__ q_ws,   // [B*H][N][16]
    const __bf16* __restrict__ k_ws,   // [B*H][N][16]
    const __bf16* __restrict__ v_ws,   // [B*H][16][N]
    __bf16* __restrict__ attn_ws)      // [B][N][128]
{
    __shared__ __align__(16) char p_lds[4][2][32 * PSTR];  // 20.5 KB
    int bh   = blockIdx.y;
    int b    = bh >> 3, h = bh & 7;
    int wave = threadIdx.x >> 6;
    int lane = threadIdx.x & 63;
    int l5   = lane & 31, hi = lane >> 5;       // 32x32 frag coords
    int quad = lane >> 4, colid = lane & 15;    // 16x16 frag coords
    int nq0  = (blockIdx.x * 4 + wave) * 32;    // this wave: 32 queries

    const __bf16* qp = q_ws + (size_t)bh * NPOS * 16;
    const __bf16* kp = k_ws + (size_t)bh * NPOS * 16;
    const __bf16* vp = v_ws + (size_t)bh * 16 * NPOS;

    // Q B-frag (32x32x16): lane holds Q[nq0+l5][hi*8 .. hi*8+7]
    bf16x8 qB = load8(qp + (size_t)(nq0 + l5) * 16 + hi * 8);

    bf16x8 ones;
#pragma unroll
    for (int i = 0; i < 8; ++i) ones[i] = (__bf16)1.0f;

    f32x4 o1 = fzero4(), o2 = fzero4(), s1 = fzero4(), s2 = fzero4();

#pragma unroll 2
    for (int nk0 = 0; nk0 < NPOS; nk0 += 32) {
        char* pbuf = p_lds[wave][(nk0 >> 5) & 1];
        // K A-frag (32x32x16): lane holds K[nk0+l5][hi*8 .. hi*8+7]
        bf16x8 kA = load8(kp + (size_t)(nk0 + l5) * 16 + hi * 8);
        f32x16 st;
#pragma unroll
        for (int i = 0; i < 16; ++i) st[i] = 0.0f;
        st = __builtin_amdgcn_mfma_f32_32x32x16_bf16(kA, qB, st, 0, 0, 0);
        // st[reg]: key = nk0 + (reg&3) + 8*(reg>>2) + 4*hi, query = nq0 + l5.
#pragma unroll
        for (int g = 0; g < 4; ++g) {
            unsigned u0 = __builtin_bit_cast(unsigned, fexp2(st[4 * g + 0])) + 0x8000u;
            unsigned u1 = __builtin_bit_cast(unsigned, fexp2(st[4 * g + 1])) + 0x8000u;
            unsigned u2 = __builtin_bit_cast(unsigned, fexp2(st[4 * g + 2])) + 0x8000u;
            unsigned u3 = __builtin_bit_cast(unsigned, fexp2(st[4 * g + 3])) + 0x8000u;
            uint2 d;
            d.x = __builtin_amdgcn_perm(u1, u0, 0x07060302u);
            d.y = __builtin_amdgcn_perm(u3, u2, 0x07060302u);
            *reinterpret_cast<uint2*>(pbuf + l5 * PSTR + (8 * g + 4 * hi) * 2) = d;
        }
        // PV (16x16x32): A = V^T (16B contig), B = P^T strips from LDS.
        bf16x8 vA = load8(vp + (size_t)colid * NPOS + nk0 + quad * 8);
        bf16x8 p1 = *reinterpret_cast<bf16x8*>(pbuf + colid * PSTR + quad * 16);
        bf16x8 p2 = *reinterpret_cast<bf16x8*>(pbuf + (colid + 16) * PSTR + quad * 16);
        o1 = __builtin_amdgcn_mfma_f32_16x16x32_bf16(vA, p1, o1, 0, 0, 0);
        s1 = __builtin_amdgcn_mfma_f32_16x16x32_bf16(ones, p1, s1, 0, 0, 0);
        o2 = __builtin_amdgcn_mfma_f32_16x16x32_bf16(vA, p2, o2, 0, 0, 0);
        s2 = __builtin_amdgcn_mfma_f32_16x16x32_bf16(ones, p2, s2, 0, 0, 0);
    }
    float inv1 = 1.0f / s1[0];
    float inv2 = 1.0f / s2[0];
    bf16x4 ov1, ov2;
#pragma unroll
    for (int r = 0; r < 4; ++r) {
        ov1[r] = (__bf16)(o1[r] * inv1);
        ov2[r] = (__bf16)(o2[r] * inv2);
    }
    *reinterpret_cast<bf16x4*>(
        attn_ws + ((size_t)b * NPOS + nq0 + colid) * DVC + h * 16 + quad * 4) = ov1;
    *reinterpret_cast<bf16x4*>(
        attn_ws + ((size_t)b * NPOS + nq0 + 16 + colid) * DVC + h * 16 + quad * 4) = ov2;
}

// ---------------------------------------------------------------------------
// Kernel 3: attention output projection. grid (N/64=16, 2, B), block 256.
// ---------------------------------------------------------------------------
__global__ __launch_bounds__(256) void attn_proj(
    const __bf16* __restrict__ attn_ws,  // [B][N][128]
    const __bf16* __restrict__ w_attn,   // [128][128]
    const __bf16* __restrict__ b_attn,   // [128]
    void* __restrict__ out,
    const int* __restrict__ flag)
{
    bool isf32 = (*flag != 0);
    int b    = blockIdx.z;
    int mt   = blockIdx.y;
    int nt   = blockIdx.x;
    int wave = threadIdx.x >> 6;
    int lane = threadIdx.x & 63;
    int quad = lane >> 4, colid = lane & 15;

    int row0 = mt * 64 + wave * 16;
    int n0   = nt * 64;
    const __bf16* ap = attn_ws + ((size_t)b * NPOS + n0) * DVC;

    f32x4 acc[4];
#pragma unroll
    for (int st = 0; st < 4; ++st) acc[st] = fzero4();

#pragma unroll
    for (int k0 = 0; k0 < DVC; k0 += 32) {
        bf16x8 a = load8(w_attn + (size_t)(row0 + colid) * DVC + k0 + quad * 8);
#pragma unroll
        for (int st = 0; st < 4; ++st) {
            bf16x8 bb = load8(ap + (size_t)(st * 16 + colid) * DVC + k0 + quad * 8);
            acc[st] = __builtin_amdgcn_mfma_f32_16x16x32_bf16(a, bb, acc[st], 0, 0, 0);
        }
    }
#pragma unroll
    for (int r = 0; r < 4; ++r) {
        int o = row0 + quad * 4 + r;
        float bias = (float)b_attn[o];
#pragma unroll
        for (int st = 0; st < 4; ++st) {
            int n = n0 + st * 16 + colid;
            float v = acc[st][r] + bias;
            size_t oi = ((size_t)b * OUTC + DVC + o) * NPOS + n;
            if (isf32) ((float*)out)[oi] = v;
            else       ((__bf16*)out)[oi] = (__bf16)v;
        }
    }
}

// ---------------------------------------------------------------------------
// Workspace layout (bytes):
//   0       : flag (int)
//   1.00 MB : w_qkvc   1.25 MB : b_qkvc   1.50 MB : w_attnc
//   1.75 MB : b_attnc  2.00 MB : w_outc   2.25 MB : b_outc
//   4  MB : xT (16MB)   20 MB : attn_ws (8MB)
//   32 MB : q_ws  40 MB : k_ws  48 MB : v_ws
// ---------------------------------------------------------------------------
extern "C" void kernel_launch(void* const* d_in, const int* in_sizes, int n_in,
                              void* d_out, int out_size, void* d_ws, size_t ws_size,
                              hipStream_t stream) {
    const void* x      = d_in[0];
    const void* w_qkv  = d_in[1];
    const void* b_qkv  = d_in[2];
    const void* w_attn = d_in[3];
    const void* b_attn = d_in[4];
    const void* w_out  = d_in[5];
    const void* b_out  = d_in[6];

    char* ws = (char*)d_ws;
    int*    flag    = (int*)ws;
    __bf16* w_qkvc  = (__bf16*)(ws + (1u << 20));
    __bf16* b_qkvc  = (__bf16*)(ws + (5u << 18));
    __bf16* w_attnc = (__bf16*)(ws + (6u << 18));
    __bf16* b_attnc = (__bf16*)(ws + (7u << 18));
    __bf16* w_outc  = (__bf16*)(ws + (8u << 18));
    __bf16* b_outc  = (__bf16*)(ws + (9u << 18));
    __bf16* xT      = (__bf16*)(ws + (4u << 20));
    __bf16* attn_ws = (__bf16*)(ws + (20u << 20));
    __bf16* q_ws    = (__bf16*)(ws + (32u << 20));
    __bf16* k_ws    = (__bf16*)(ws + (40u << 20));
    __bf16* v_ws    = (__bf16*)(ws + (48u << 20));

    detect_dtype<<<1, 256, 0, stream>>>((const unsigned short*)x, flag);
    convert_all<<<(CVT_N5 + 255) / 256, 256, 0, stream>>>(
        w_qkv, b_qkv, w_attn, b_attn, w_out, b_out,
        w_qkvc, b_qkvc, w_attnc, b_attnc, w_outc, b_outc, flag);

    transpose_x<<<dim3(NPOS / 64, CIN / 64, BATCH), 256, 0, stream>>>(x, xT, flag);
    qkv_conv_gemm<<<dim3(NPOS / 64, 8, BATCH), 256, 0, stream>>>(
        xT, w_qkvc, b_qkvc, w_outc, b_outc, q_ws, k_ws, v_ws, d_out, flag);
    attention_kernel<<<dim3(NPOS / 128, BATCH * HEADS), 256, 0, stream>>>(
        q_ws, k_ws, v_ws, attn_ws);
    attn_proj<<<dim3(NPOS / 64, 2, BATCH), 256, 0, stream>>>(
        attn_ws, w_attnc, b_attnc, d_out, flag);
}

// Round 9
// 220.538 us; speedup vs baseline: 1.1481x; 1.1481x over previous
//
#include <hip/hip_runtime.h>
#include <hip/hip_bf16.h>

// Problem constants (AttentionConv2d): B=32, CIN=256, H=W=32 -> N=1024,
// DK=DV=128, HEADS=8 -> per-head d=16, OUT=256.
#define BATCH 32
#define CIN   256
#define NPOS  1024
#define DKC   128
#define DVC   128
#define HEADS 8
#define OUTC  256

typedef __bf16 bf16x8 __attribute__((ext_vector_type(8)));
typedef __bf16 bf16x4 __attribute__((ext_vector_type(4)));
typedef float  f32x4  __attribute__((ext_vector_type(4)));
typedef float  f32x16 __attribute__((ext_vector_type(16)));

// q pre-scale: dk^-0.5 * log2(e), so attention can use raw exp2.
#define QSCALE 0.3606737602f

__device__ inline bf16x8 load8(const __bf16* p) {
    return *reinterpret_cast<const bf16x8*>(p);
}
__device__ inline f32x4 fzero4() {
    f32x4 z;
#pragma unroll
    for (int i = 0; i < 4; ++i) z[i] = 0.0f;
    return z;
}
__device__ inline float fexp2(float x) {
#if __has_builtin(__builtin_amdgcn_exp2f)
    return __builtin_amdgcn_exp2f(x);
#else
    return exp2f(x);
#endif
}

// ---------------------------------------------------------------------------
// Kernel D: dtype detector (fp32-as-bf16 halfwords have huge exponents).
// ---------------------------------------------------------------------------
__global__ __launch_bounds__(256) void detect_dtype(const unsigned short* __restrict__ xraw,
                                                    int* __restrict__ flag) {
    __shared__ int s;
    if (threadIdx.x == 0) s = 0;
    __syncthreads();
    int cnt = 0;
#pragma unroll
    for (int j = 0; j < 64; ++j) {
        unsigned short u = xraw[threadIdx.x * 64 + j];
        unsigned int e = (u >> 7) & 0xFF;
        if (e >= 0x92) cnt++;
    }
    if (cnt) atomicAdd(&s, cnt);
    __syncthreads();
    if (threadIdx.x == 0) *flag = (s > 0) ? 1 : 0;
}

// ---------------------------------------------------------------------------
// Kernel C: convert all weight/bias tensors to canonical bf16 in one launch.
// ---------------------------------------------------------------------------
#define CVT_N0 98304   // w_qkv 384*256
#define CVT_N1 (CVT_N0 + 384)
#define CVT_N2 (CVT_N1 + 16384)  // w_attn 128*128
#define CVT_N3 (CVT_N2 + 128)
#define CVT_N4 (CVT_N3 + 32768)  // w_out 128*256
#define CVT_N5 (CVT_N4 + 128)
__global__ __launch_bounds__(256) void convert_all(
    const void* __restrict__ w_qkv, const void* __restrict__ b_qkv,
    const void* __restrict__ w_attn, const void* __restrict__ b_attn,
    const void* __restrict__ w_out, const void* __restrict__ b_out,
    __bf16* __restrict__ w_qkvc, __bf16* __restrict__ b_qkvc,
    __bf16* __restrict__ w_attnc, __bf16* __restrict__ b_attnc,
    __bf16* __restrict__ w_outc, __bf16* __restrict__ b_outc,
    const int* __restrict__ flag) {
    int i = blockIdx.x * 256 + threadIdx.x;
    const void* src; __bf16* dst; int off;
    if      (i < CVT_N0) { src = w_qkv;  dst = w_qkvc;  off = 0; }
    else if (i < CVT_N1) { src = b_qkv;  dst = b_qkvc;  off = CVT_N0; }
    else if (i < CVT_N2) { src = w_attn; dst = w_attnc; off = CVT_N1; }
    else if (i < CVT_N3) { src = b_attn; dst = b_attnc; off = CVT_N2; }
    else if (i < CVT_N4) { src = w_out;  dst = w_outc;  off = CVT_N3; }
    else if (i < CVT_N5) { src = b_out;  dst = b_outc;  off = CVT_N4; }
    else return;
    int j = i - off;
    if (*flag) dst[j] = (__bf16)((const float*)src)[j];
    else       dst[j] = ((const __bf16*)src)[j];
}

// ---------------------------------------------------------------------------
// Kernel 0: transpose+convert x [B][C][N] -> xT(bf16) [B][N][C] (unchanged).
// grid (N/64=16, C/64=4, B=32), block 256.
// ---------------------------------------------------------------------------
__global__ __launch_bounds__(256) void transpose_x(const void* __restrict__ xv,
                                                   __bf16* __restrict__ xT,
                                                   const int* __restrict__ flag) {
    __shared__ __bf16 tile[64][68];
    bool isf32 = (*flag != 0);
    int b  = blockIdx.z;
    int n0 = blockIdx.x * 64;
    int c0 = blockIdx.y * 64;
    int t  = threadIdx.x;

    int nl = (t & 15) * 4;
    int cl = t >> 4;
#pragma unroll
    for (int i = 0; i < 4; ++i) {
        int c = cl + i * 16;
        size_t base = ((size_t)b * CIN + c0 + c) * NPOS + n0 + nl;
        if (isf32) {
            float4 v = *reinterpret_cast<const float4*>((const float*)xv + base);
            tile[c][nl + 0] = (__bf16)v.x;
            tile[c][nl + 1] = (__bf16)v.y;
            tile[c][nl + 2] = (__bf16)v.z;
            tile[c][nl + 3] = (__bf16)v.w;
        } else {
            bf16x4 v = *reinterpret_cast<const bf16x4*>((const __bf16*)xv + base);
#pragma unroll
            for (int j = 0; j < 4; ++j) tile[c][nl + j] = v[j];
        }
    }
    __syncthreads();
    int cl2 = (t & 15) * 4;
    int nl2 = t >> 4;
#pragma unroll
    for (int i = 0; i < 4; ++i) {
        int n = nl2 + i * 16;
        bf16x4 v;
#pragma unroll
        for (int j = 0; j < 4; ++j) v[j] = tile[cl2 + j][n];
        *reinterpret_cast<bf16x4*>(
            xT + ((size_t)b * NPOS + n0 + n) * CIN + c0 + cl2) = v;
    }
}

// ---------------------------------------------------------------------------
// Kernel 1: QKV + conv GEMM, 64x64 PER WAVE (16 independent MFMA per k-step,
// loads/MFMA = 0.5 — fixes the 4-MFMA/5-load latency churn of the old tile).
// xT is flat [B*N][C]; block covers 128 flat-cols x 128 rows (2x2 waves).
// rows 0..383 = w_qkv (q/k/v), 384..511 = w_out -> d_out channels 0..127.
// grid (B*N/128=256, M/128=4), block 256. acc 64 VGPR -> ~4 waves/SIMD.
// ---------------------------------------------------------------------------
__global__ __launch_bounds__(256) void qkv_conv_gemm(
    const __bf16* __restrict__ xT,     // [B*N][C]
    const __bf16* __restrict__ w_qkv,  // [384][256]
    const __bf16* __restrict__ b_qkv,  // [384]
    const __bf16* __restrict__ w_out,  // [128][256]
    const __bf16* __restrict__ b_out,  // [128]
    __bf16* __restrict__ q_ws,         // [B*H][N][16]
    __bf16* __restrict__ k_ws,         // [B*H][N][16]
    __bf16* __restrict__ v_ws,         // [B*H][16][N]
    void* __restrict__ out,            // [B][256][N], dtype per flag
    const int* __restrict__ flag)
{
    bool isf32 = (*flag != 0);
    int wave = threadIdx.x >> 6;
    int lane = threadIdx.x & 63;
    int quad = lane >> 4, colid = lane & 15;

    int p0 = blockIdx.x * 128 + (wave & 1) * 64;   // flat b*N+n (within one b)
    int m0 = blockIdx.y * 128 + (wave >> 1) * 64;  // output row

    const __bf16* xb = xT + (size_t)p0 * CIN;
    // per-row-tile weight base (wave-uniform; 384 boundary is tile-aligned)
    const __bf16* wbase[4];
#pragma unroll
    for (int rt = 0; rt < 4; ++rt) {
        int rowt = m0 + rt * 16;
        wbase[rt] = (rowt < 384) ? (w_qkv + (size_t)rowt * CIN)
                                 : (w_out + (size_t)(rowt - 384) * CIN);
    }

    f32x4 acc[4][4];
#pragma unroll
    for (int rt = 0; rt < 4; ++rt)
#pragma unroll
        for (int st = 0; st < 4; ++st) acc[rt][st] = fzero4();

#pragma unroll
    for (int k0 = 0; k0 < CIN; k0 += 32) {
        bf16x8 av[4], bv[4];
#pragma unroll
        for (int rt = 0; rt < 4; ++rt)
            av[rt] = load8(wbase[rt] + (size_t)colid * CIN + k0 + quad * 8);
#pragma unroll
        for (int st = 0; st < 4; ++st)
            bv[st] = load8(xb + (size_t)(st * 16 + colid) * CIN + k0 + quad * 8);
#pragma unroll
        for (int rt = 0; rt < 4; ++rt)
#pragma unroll
            for (int st = 0; st < 4; ++st)
                acc[rt][st] = __builtin_amdgcn_mfma_f32_16x16x32_bf16(av[rt], bv[st], acc[rt][st], 0, 0, 0);
    }

#pragma unroll
    for (int rt = 0; rt < 4; ++rt) {
#pragma unroll
        for (int r = 0; r < 4; ++r) {
            int o = m0 + rt * 16 + quad * 4 + r;
            float bias = (o < 384) ? (float)b_qkv[o] : (float)b_out[o - 384];
#pragma unroll
            for (int st = 0; st < 4; ++st) {
                int p = p0 + st * 16 + colid;
                int b = p >> 10, n = p & 1023;
                float v = acc[rt][st][r] + bias;
                if (o < DKC) {  // q, pre-scaled for exp2 softmax
                    int h = o >> 4, d = o & 15;
                    q_ws[(((size_t)b * HEADS + h) * NPOS + n) * 16 + d] = (__bf16)(v * QSCALE);
                } else if (o < 2 * DKC) {  // k
                    int oo = o - DKC;
                    k_ws[(((size_t)b * HEADS + (oo >> 4)) * NPOS + n) * 16 + (oo & 15)] = (__bf16)v;
                } else if (o < 384) {  // v -> [bh][d][n]
                    int oo = o - 2 * DKC;
                    v_ws[(((size_t)b * HEADS + (oo >> 4)) * 16 + (oo & 15)) * NPOS + n] = (__bf16)v;
                } else {  // conv branch -> output channels 0..127
                    size_t oi = ((size_t)b * OUTC + (o - 384)) * NPOS + n;
                    if (isf32) ((float*)out)[oi] = v;
                    else       ((__bf16*)out)[oi] = (__bf16)v;
                }
            }
        }
    }
}

// ---------------------------------------------------------------------------
// Kernel 2: attention on NATIVE MFMA shapes (unchanged from round 7).
// grid (N/128=8, B*H=256), block 256 (4 independent waves).
// ---------------------------------------------------------------------------
#define PSTR 80  // bytes per query row in the P strip (16B-aligned, odd*16)
__global__ __launch_bounds__(256) void attention_kernel(
    const __bf16* __restrict__ q_ws,   // [B*H][N][16]
    const __bf16* __restrict__ k_ws,   // [B*H][N][16]
    const __bf16* __restrict__ v_ws,   // [B*H][16][N]
    __bf16* __restrict__ attn_ws)      // [B][N][128]
{
    __shared__ __align__(16) char p_lds[4][2][32 * PSTR];  // 20.5 KB
    int bh   = blockIdx.y;
    int b    = bh >> 3, h = bh & 7;
    int wave = threadIdx.x >> 6;
    int lane = threadIdx.x & 63;
    int l5   = lane & 31, hi = lane >> 5;       // 32x32 frag coords
    int quad = lane >> 4, colid = lane & 15;    // 16x16 frag coords
    int nq0  = (blockIdx.x * 4 + wave) * 32;    // this wave: 32 queries

    const __bf16* qp = q_ws + (size_t)bh * NPOS * 16;
    const __bf16* kp = k_ws + (size_t)bh * NPOS * 16;
    const __bf16* vp = v_ws + (size_t)bh * 16 * NPOS;

    // Q B-frag (32x32x16): lane holds Q[nq0+l5][hi*8 .. hi*8+7]
    bf16x8 qB = load8(qp + (size_t)(nq0 + l5) * 16 + hi * 8);

    bf16x8 ones;
#pragma unroll
    for (int i = 0; i < 8; ++i) ones[i] = (__bf16)1.0f;

    f32x4 o1 = fzero4(), o2 = fzero4(), s1 = fzero4(), s2 = fzero4();

#pragma unroll 2
    for (int nk0 = 0; nk0 < NPOS; nk0 += 32) {
        char* pbuf = p_lds[wave][(nk0 >> 5) & 1];
        // K A-frag (32x32x16): lane holds K[nk0+l5][hi*8 .. hi*8+7]
        bf16x8 kA = load8(kp + (size_t)(nk0 + l5) * 16 + hi * 8);
        f32x16 st;
#pragma unroll
        for (int i = 0; i < 16; ++i) st[i] = 0.0f;
        st = __builtin_amdgcn_mfma_f32_32x32x16_bf16(kA, qB, st, 0, 0, 0);
        // st[reg]: key = nk0 + (reg&3) + 8*(reg>>2) + 4*hi, query = nq0 + l5.
#pragma unroll
        for (int g = 0; g < 4; ++g) {
            unsigned u0 = __builtin_bit_cast(unsigned, fexp2(st[4 * g + 0])) + 0x8000u;
            unsigned u1 = __builtin_bit_cast(unsigned, fexp2(st[4 * g + 1])) + 0x8000u;
            unsigned u2 = __builtin_bit_cast(unsigned, fexp2(st[4 * g + 2])) + 0x8000u;
            unsigned u3 = __builtin_bit_cast(unsigned, fexp2(st[4 * g + 3])) + 0x8000u;
            uint2 d;
            d.x = __builtin_amdgcn_perm(u1, u0, 0x07060302u);
            d.y = __builtin_amdgcn_perm(u3, u2, 0x07060302u);
            *reinterpret_cast<uint2*>(pbuf + l5 * PSTR + (8 * g + 4 * hi) * 2) = d;
        }
        // PV (16x16x32): A = V^T (16B contig), B = P^T strips from LDS.
        bf16x8 vA = load8(vp + (size_t)colid * NPOS + nk0 + quad * 8);
        bf16x8 p1 = *reinterpret_cast<bf16x8*>(pbuf + colid * PSTR + quad * 16);
        bf16x8 p2 = *reinterpret_cast<bf16x8*>(pbuf + (colid + 16) * PSTR + quad * 16);
        o1 = __builtin_amdgcn_mfma_f32_16x16x32_bf16(vA, p1, o1, 0, 0, 0);
        s1 = __builtin_amdgcn_mfma_f32_16x16x32_bf16(ones, p1, s1, 0, 0, 0);
        o2 = __builtin_amdgcn_mfma_f32_16x16x32_bf16(vA, p2, o2, 0, 0, 0);
        s2 = __builtin_amdgcn_mfma_f32_16x16x32_bf16(ones, p2, s2, 0, 0, 0);
    }
    float inv1 = 1.0f / s1[0];
    float inv2 = 1.0f / s2[0];
    bf16x4 ov1, ov2;
#pragma unroll
    for (int r = 0; r < 4; ++r) {
        ov1[r] = (__bf16)(o1[r] * inv1);
        ov2[r] = (__bf16)(o2[r] * inv2);
    }
    *reinterpret_cast<bf16x4*>(
        attn_ws + ((size_t)b * NPOS + nq0 + colid) * DVC + h * 16 + quad * 4) = ov1;
    *reinterpret_cast<bf16x4*>(
        attn_ws + ((size_t)b * NPOS + nq0 + 16 + colid) * DVC + h * 16 + quad * 4) = ov2;
}

// ---------------------------------------------------------------------------
// Kernel 3: attention output projection, 64x64 per wave (same restructure).
// attn_ws flat [B*N][128]; block = 128 rows (all of M) x 128 flat-cols.
// grid (B*N/128=256), block 256.
// ---------------------------------------------------------------------------
__global__ __launch_bounds__(256) void attn_proj(
    const __bf16* __restrict__ attn_ws,  // [B*N][128]
    const __bf16* __restrict__ w_attn,   // [128][128]
    const __bf16* __restrict__ b_attn,   // [128]
    void* __restrict__ out,
    const int* __restrict__ flag)
{
    bool isf32 = (*flag != 0);
    int wave = threadIdx.x >> 6;
    int lane = threadIdx.x & 63;
    int quad = lane >> 4, colid = lane & 15;

    int p0 = blockIdx.x * 128 + (wave & 1) * 64;
    int m0 = (wave >> 1) * 64;
    const __bf16* ap = attn_ws + (size_t)p0 * DVC;

    f32x4 acc[4][4];
#pragma unroll
    for (int rt = 0; rt < 4; ++rt)
#pragma unroll
        for (int st = 0; st < 4; ++st) acc[rt][st] = fzero4();

#pragma unroll
    for (int k0 = 0; k0 < DVC; k0 += 32) {
        bf16x8 av[4], bv[4];
#pragma unroll
        for (int rt = 0; rt < 4; ++rt)
            av[rt] = load8(w_attn + (size_t)(m0 + rt * 16 + colid) * DVC + k0 + quad * 8);
#pragma unroll
        for (int st = 0; st < 4; ++st)
            bv[st] = load8(ap + (size_t)(st * 16 + colid) * DVC + k0 + quad * 8);
#pragma unroll
        for (int rt = 0; rt < 4; ++rt)
#pragma unroll
            for (int st = 0; st < 4; ++st)
                acc[rt][st] = __builtin_amdgcn_mfma_f32_16x16x32_bf16(av[rt], bv[st], acc[rt][st], 0, 0, 0);
    }

#pragma unroll
    for (int rt = 0; rt < 4; ++rt) {
#pragma unroll
        for (int r = 0; r < 4; ++r) {
            int o = m0 + rt * 16 + quad * 4 + r;
            float bias = (float)b_attn[o];
#pragma unroll
            for (int st = 0; st < 4; ++st) {
                int p = p0 + st * 16 + colid;
                int b = p >> 10, n = p & 1023;
                float v = acc[rt][st][r] + bias;
                size_t oi = ((size_t)b * OUTC + DVC + o) * NPOS + n;
                if (isf32) ((float*)out)[oi] = v;
                else       ((__bf16*)out)[oi] = (__bf16)v;
            }
        }
    }
}

// ---------------------------------------------------------------------------
// Workspace layout (bytes):
//   0       : flag (int)
//   1.00 MB : w_qkvc   1.25 MB : b_qkvc   1.50 MB : w_attnc
//   1.75 MB : b_attnc  2.00 MB : w_outc   2.25 MB : b_outc
//   4  MB : xT (16MB)   20 MB : attn_ws (8MB)
//   32 MB : q_ws  40 MB : k_ws  48 MB : v_ws
// ---------------------------------------------------------------------------
extern "C" void kernel_launch(void* const* d_in, const int* in_sizes, int n_in,
                              void* d_out, int out_size, void* d_ws, size_t ws_size,
                              hipStream_t stream) {
    const void* x      = d_in[0];
    const void* w_qkv  = d_in[1];
    const void* b_qkv  = d_in[2];
    const void* w_attn = d_in[3];
    const void* b_attn = d_in[4];
    const void* w_out  = d_in[5];
    const void* b_out  = d_in[6];

    char* ws = (char*)d_ws;
    int*    flag    = (int*)ws;
    __bf16* w_qkvc  = (__bf16*)(ws + (1u << 20));
    __bf16* b_qkvc  = (__bf16*)(ws + (5u << 18));
    __bf16* w_attnc = (__bf16*)(ws + (6u << 18));
    __bf16* b_attnc = (__bf16*)(ws + (7u << 18));
    __bf16* w_outc  = (__bf16*)(ws + (8u << 18));
    __bf16* b_outc  = (__bf16*)(ws + (9u << 18));
    __bf16* xT      = (__bf16*)(ws + (4u << 20));
    __bf16* attn_ws = (__bf16*)(ws + (20u << 20));
    __bf16* q_ws    = (__bf16*)(ws + (32u << 20));
    __bf16* k_ws    = (__bf16*)(ws + (40u << 20));
    __bf16* v_ws    = (__bf16*)(ws + (48u << 20));

    detect_dtype<<<1, 256, 0, stream>>>((const unsigned short*)x, flag);
    convert_all<<<(CVT_N5 + 255) / 256, 256, 0, stream>>>(
        w_qkv, b_qkv, w_attn, b_attn, w_out, b_out,
        w_qkvc, b_qkvc, w_attnc, b_attnc, w_outc, b_outc, flag);

    transpose_x<<<dim3(NPOS / 64, CIN / 64, BATCH), 256, 0, stream>>>(x, xT, flag);
    qkv_conv_gemm<<<dim3(BATCH * NPOS / 128, 512 / 128), 256, 0, stream>>>(
        xT, w_qkvc, b_qkvc, w_outc, b_outc, q_ws, k_ws, v_ws, d_out, flag);
    attention_kernel<<<dim3(NPOS / 128, BATCH * HEADS), 256, 0, stream>>>(
        q_ws, k_ws, v_ws, attn_ws);
    attn_proj<<<dim3(BATCH * NPOS / 128), 256, 0, stream>>>(
        attn_ws, w_attnc, b_attnc, d_out, flag);
}